// Round 6
// baseline (168.002 us; speedup 1.0000x reference)
//
#include <hip/hip_runtime.h>

// ActorGCN collapsed-linear implementation.
// Key identity: A(xW) = (Ax)W, and BN stats of h = yW+b reduce to the
// 20x20 covariance of y. Hidden [N,1024] never materialized.
//
// Workspace layout (floats):
//   deg   : [0,   N)
//   dinv  : [N,  2N)
//   y     : [2N, 2N + 20N)
//   stats : 256 floats (20 column sums + 210 upper-tri second moments)
//   params: 64 floats  (M[40], d[2], ybar[20])
// Total = 22N + 320 floats ~= 18.4 MB.
//
// Round 6: no hipMemsetAsync in the graph (round-5 profile showed the 1KB
// fillBufferAligned costing ~41 us/replay); stats zeroed by k_deg_init.
// Scatter/selfloop/stats-fill vectorized to float4 (rows are 20 floats =
// 5 quads, 16B-aligned at 80B row pitch).

#define F 20
#define NSTAT 230  // 20 sums + 210 upper-triangle (incl diag) products

// deg[n] = 1 (self-loop); block 0 also zeroes the 256-float stats buffer,
// replacing the graph-captured memset node.
__global__ void k_deg_init(float* __restrict__ deg, float* __restrict__ stats, int N) {
  int n = blockIdx.x * blockDim.x + threadIdx.x;
  if (n < N) deg[n] = 1.0f;
  if (n < 256) stats[n] = 0.f;
}

__global__ void k_deg_acc(const int* __restrict__ dst, float* __restrict__ deg, int E) {
  int e = blockIdx.x * blockDim.x + threadIdx.x;
  if (e < E) atomicAdd(&deg[dst[e]], 1.0f);
}

// thread per (node, quad): y[n, 4q..4q+3] = x[n, 4q..4q+3]/deg[n].
// q==0 thread also emits dinv[n] = rsqrt(deg[n]).
__global__ void k_selfloop(const float* __restrict__ state,
                           const float* __restrict__ edge_attr,
                           const float* __restrict__ deg,
                           float* __restrict__ dinv,
                           float* __restrict__ y,
                           int N, int Ns) {
  int tid = blockIdx.x * blockDim.x + threadIdx.x;
  if (tid >= N * 5) return;
  int n = tid / 5;
  int q = tid - n * 5;
  float d = deg[n];
  float inv = 1.0f / d;
  const float* xrow = (n < Ns) ? (state + (size_t)n * F)
                               : (edge_attr + (size_t)(n - Ns) * F);
  float4 v = *reinterpret_cast<const float4*>(xrow + q * 4);
  v.x *= inv; v.y *= inv; v.z *= inv; v.w *= inv;
  *reinterpret_cast<float4*>(y + (size_t)n * F + q * 4) = v;
  if (q == 0) dinv[n] = rsqrtf(d);
}

// thread per (edge, quad): y[dst, 4q..4q+3] += norm * x[src, 4q..4q+3].
// One dwordx4 gather + 4 atomics per thread; src/dst/dinv redundancy 5x
// (was 20x with thread-per-(edge,feature)).
__global__ void k_edge_scatter(const int* __restrict__ src,
                               const int* __restrict__ dst,
                               const float* __restrict__ dinv,
                               const float* __restrict__ state,
                               const float* __restrict__ edge_attr,
                               float* __restrict__ y,
                               int E, int Ns) {
  int tid = blockIdx.x * blockDim.x + threadIdx.x;
  if (tid >= E * 5) return;
  int e = tid / 5;
  int q = tid - e * 5;
  int s = src[e];
  int d = dst[e];
  float norm = dinv[s] * dinv[d];
  const float* xrow = (s < Ns) ? (state + (size_t)s * F)
                               : (edge_attr + (size_t)(s - Ns) * F);
  float4 v = *reinterpret_cast<const float4*>(xrow + q * 4);
  float* yr = y + (size_t)d * F + q * 4;
  atomicAdd(yr + 0, norm * v.x);
  atomicAdd(yr + 1, norm * v.y);
  atomicAdd(yr + 2, norm * v.z);
  atomicAdd(yr + 3, norm * v.w);
}

// Column sums + upper-tri second moments of y, LDS-staged.
// One 256-row chunk per block (814 blocks, ~12 waves/CU TLP); row loop
// unrolled x4 with independent accumulators; one atomicAdd per stat per block.
#define SROWS 256
__global__ __launch_bounds__(256) void k_stats(const float* __restrict__ y,
                                               float* __restrict__ stats, int N) {
  __shared__ float lds[SROWS * F];  // 20 KB
  int c = threadIdx.x;
  int ci = 0, cj = 0;
  if (c >= F && c < NSTAT) {
    int k = c - F;
    int i = 0;
    while (k >= F - i) { k -= F - i; i++; }
    ci = i; cj = i + k;
  }
  long e0 = (long)blockIdx.x * (SROWS * F);
  long totalElems = (long)N * F;
  // quad-vectorized fill: 5120 floats = 1280 quads; tail is quad-aligned
  // (N*F and e0 are both multiples of 4).
  for (int i4 = c; i4 < SROWS * F / 4; i4 += 256) {
    long gi = e0 + (long)i4 * 4;
    float4 v;
    if (gi + 3 < totalElems) {
      v = *reinterpret_cast<const float4*>(y + gi);
    } else {
      v.x = v.y = v.z = v.w = 0.f;
    }
    *reinterpret_cast<float4*>(lds + i4 * 4) = v;
  }
  __syncthreads();
  if (c < F) {
    float a0 = 0.f, a1 = 0.f, a2 = 0.f, a3 = 0.f;
    for (int r = 0; r < SROWS; r += 4) {
      a0 += lds[(r + 0) * F + c];
      a1 += lds[(r + 1) * F + c];
      a2 += lds[(r + 2) * F + c];
      a3 += lds[(r + 3) * F + c];
    }
    atomicAdd(&stats[c], (a0 + a1) + (a2 + a3));
  } else if (c < NSTAT) {
    float a0 = 0.f, a1 = 0.f, a2 = 0.f, a3 = 0.f;
    for (int r = 0; r < SROWS; r += 4) {
      a0 += lds[(r + 0) * F + ci] * lds[(r + 0) * F + cj];
      a1 += lds[(r + 1) * F + ci] * lds[(r + 1) * F + cj];
      a2 += lds[(r + 2) * F + ci] * lds[(r + 2) * F + cj];
      a3 += lds[(r + 3) * F + ci] * lds[(r + 3) * F + cj];
    }
    atomicAdd(&stats[c], (a0 + a1) + (a2 + a3));
  }
}

// Single block, 256 threads, launch_bounds(256,1): 4 waves -> up to 512
// VGPR/thread, so w[4][20] + m0[20] + m1[20] live in registers (rounds 2-3
// at 1024 threads were capped at 64 VGPR -> scratch spill).
__global__ __launch_bounds__(256, 1) void k_finalize(
    const float* __restrict__ stats,
    const float* __restrict__ W_gcn,
    const float* __restrict__ gamma,
    const float* __restrict__ beta,
    const float* __restrict__ W_lin,
    const float* __restrict__ b_lin,
    float* __restrict__ params,
    int N, int H) {
  __shared__ float Cu_s[210];
  __shared__ float ybar_s[F];
  __shared__ float part[4][44];
  int t = threadIdx.x;
  int lane = t & 63;
  int wv = t >> 6;
  float invN = 1.0f / (float)N;
  if (t < F) ybar_s[t] = stats[t] * invN;
  __syncthreads();
  if (t < 210) {
    int k = t;
    int i = 0;
    while (k >= F - i) { k -= F - i; i++; }
    int j = i + k;
    float cv = stats[F + t] * invN - ybar_s[i] * ybar_s[j];
    Cu_s[t] = (i == j) ? cv : 2.0f * cv;  // fold symmetry factor
  }
  __syncthreads();

  float m0[F], m1[F];
  #pragma unroll
  for (int f = 0; f < F; ++f) { m0[f] = 0.f; m1[f] = 0.f; }
  float d0 = 0.f, d1 = 0.f;

  for (int hb = 0; hb < H; hb += 4 * 256) {
    float w[4][F];
    float var[4];
    int hh[4];
    bool act[4];
    #pragma unroll
    for (int c = 0; c < 4; ++c) {
      int h = hb + c * 256 + t;
      act[c] = (h < H);
      hh[c] = act[c] ? h : 0;
      var[c] = 0.f;
      #pragma unroll
      for (int f = 0; f < F; ++f) {
        float x = W_gcn[f * H + hh[c]];  // coalesced over t
        w[c][f] = act[c] ? x : 0.f;
      }
    }
    int p = 0;
    #pragma unroll
    for (int i = 0; i < F; ++i) {
      #pragma unroll
      for (int j = i; j < F; ++j) {
        float cu = Cu_s[p];  // uniform broadcast, reused 4x
        ++p;
        #pragma unroll
        for (int c = 0; c < 4; ++c) var[c] += cu * (w[c][i] * w[c][j]);
      }
    }
    #pragma unroll
    for (int c = 0; c < 4; ++c) {
      float sg = act[c] ? (gamma[hh[c]] * rsqrtf(var[c] + 1e-5f)) : 0.f;
      float wl0 = W_lin[hh[c] * 2 + 0], wl1 = W_lin[hh[c] * 2 + 1];
      float s0 = sg * wl0, s1 = sg * wl1;
      #pragma unroll
      for (int f = 0; f < F; ++f) { m0[f] += w[c][f] * s0; m1[f] += w[c][f] * s1; }
      float bt = act[c] ? beta[hh[c]] : 0.f;
      d0 += bt * wl0;
      d1 += bt * wl1;
    }
  }

  // one butterfly reduce at the end
  #pragma unroll
  for (int f = 0; f < F; ++f) {
    float v0 = m0[f], v1 = m1[f];
    #pragma unroll
    for (int off = 32; off; off >>= 1) {
      v0 += __shfl_xor(v0, off);
      v1 += __shfl_xor(v1, off);
    }
    if (lane == 0) { part[wv][2 * f] = v0; part[wv][2 * f + 1] = v1; }
  }
  #pragma unroll
  for (int off = 32; off; off >>= 1) {
    d0 += __shfl_xor(d0, off);
    d1 += __shfl_xor(d1, off);
  }
  if (lane == 0) { part[wv][40] = d0; part[wv][41] = d1; }
  __syncthreads();

  if (t < 42) {
    float acc = 0.f;
    for (int w2 = 0; w2 < 4; ++w2) acc += part[w2][t];
    if (t >= 40) acc += b_lin[t - 40];
    params[t] = acc;
  } else if (t < 62) {
    params[t] = ybar_s[t - 42];
  }
}

// thread per node: logits = (y[n]-ybar) @ M + d; relu; 2-way softmax.
__global__ void k_out(const float* __restrict__ y,
                      const float* __restrict__ params,
                      float* __restrict__ out, int N) {
  __shared__ float P[64];
  if (threadIdx.x < 62) P[threadIdx.x] = params[threadIdx.x];
  __syncthreads();
  int n = blockIdx.x * blockDim.x + threadIdx.x;
  if (n >= N) return;
  const float4* yr4 = reinterpret_cast<const float4*>(y + (size_t)n * F);
  float v[F];
  #pragma unroll
  for (int k = 0; k < 5; ++k) {
    float4 q = yr4[k];
    v[4 * k + 0] = q.x; v[4 * k + 1] = q.y;
    v[4 * k + 2] = q.z; v[4 * k + 3] = q.w;
  }
  float l0 = P[40], l1 = P[41];
  #pragma unroll
  for (int f = 0; f < F; ++f) {
    float dv = v[f] - P[42 + f];
    l0 += dv * P[f * 2 + 0];
    l1 += dv * P[f * 2 + 1];
  }
  l0 = fmaxf(l0, 0.f);
  l1 = fmaxf(l1, 0.f);
  float m = fmaxf(l0, l1);
  float e0 = __expf(l0 - m), e1 = __expf(l1 - m);
  float inv = 1.0f / (e0 + e1);
  float2 o2; o2.x = e0 * inv; o2.y = e1 * inv;
  reinterpret_cast<float2*>(out)[n] = o2;
}

extern "C" void kernel_launch(void* const* d_in, const int* in_sizes, int n_in,
                              void* d_out, int out_size, void* d_ws, size_t ws_size,
                              hipStream_t stream) {
  const float* state     = (const float*)d_in[0];
  const float* edge_attr = (const float*)d_in[1];
  const int*   eidx      = (const int*)d_in[2];
  const float* W_gcn     = (const float*)d_in[3];
  // d_in[4] = b_gcn: cancels inside batchnorm, unused.
  const float* gamma     = (const float*)d_in[5];
  const float* beta      = (const float*)d_in[6];
  const float* W_lin     = (const float*)d_in[7];
  const float* b_lin     = (const float*)d_in[8];
  float* out = (float*)d_out;

  int Ns = in_sizes[0] / F;
  int E  = in_sizes[2] / 2;
  int N  = Ns + in_sizes[1] / F;
  int H  = in_sizes[4];

  const int* src = eidx;
  const int* dst = eidx + E;

  float* ws     = (float*)d_ws;
  float* deg    = ws;
  float* dinv   = ws + N;
  float* y      = ws + 2 * (size_t)N;
  float* stats  = y + (size_t)N * F;
  float* params = stats + 256;

  const int B = 256;
  k_deg_init<<<(N + B - 1) / B, B, 0, stream>>>(deg, stats, N);
  k_deg_acc<<<(E + B - 1) / B, B, 0, stream>>>(dst, deg, E);
  k_selfloop<<<(N * 5 + B - 1) / B, B, 0, stream>>>(state, edge_attr, deg, dinv, y, N, Ns);
  k_edge_scatter<<<(E * 5 + B - 1) / B, B, 0, stream>>>(src, dst, dinv, state, edge_attr, y, E, Ns);
  k_stats<<<(N + SROWS - 1) / SROWS, B, 0, stream>>>(y, stats, N);
  k_finalize<<<1, 256, 0, stream>>>(stats, W_gcn, gamma, beta, W_lin, b_lin, params, N, H);
  k_out<<<(N + B - 1) / B, B, 0, stream>>>(y, params, out, N);
}

// Round 7
// 105.969 us; speedup vs baseline: 1.5854x; 1.5854x over previous
//
#include <hip/hip_runtime.h>

// ActorGCN collapsed-linear implementation.
// Key identity: A(xW) = (Ax)W, and BN stats of h = yW+b reduce to the
// 20x20 covariance of y. Hidden [N,1024] never materialized.
//
// Workspace layout (floats):
//   deg   : [0,   N)
//   dinv  : [N,  2N)
//   y     : [2N, 2N + 20N)
//   stats : 256 floats (20 column sums + 210 upper-tri second moments)
//   params: 64 floats  (M[40], d[2], ybar[20])
// Total = 22N + 320 floats ~= 18.4 MB.
//
// Round 7: scatter reverted to thread-per-(edge,feature) scalar atomics.
// Round-6's float4 scatter (4 serialized atomics/thread, one edge per lane)
// destroyed per-instruction line locality: WRITE_SIZE 75.8 MB vs 16.6 MB
// dest, 87 us vs <=41 us. With f-major lanes, a wave's 64 lanes span ~3
// edges -> each atomic instruction touches ~7 cache lines, not 64.

#define F 20
#define NSTAT 230  // 20 sums + 210 upper-triangle (incl diag) products

// deg[n] = 1 (self-loop); also zeroes the 256-float stats buffer,
// replacing the graph-captured memset node (round-5 profile: 1KB
// fillBufferAligned cost ~41 us/replay).
__global__ void k_deg_init(float* __restrict__ deg, float* __restrict__ stats, int N) {
  int n = blockIdx.x * blockDim.x + threadIdx.x;
  if (n < N) deg[n] = 1.0f;
  if (n < 256) stats[n] = 0.f;
}

__global__ void k_deg_acc(const int* __restrict__ dst, float* __restrict__ deg, int E) {
  int e = blockIdx.x * blockDim.x + threadIdx.x;
  if (e < E) atomicAdd(&deg[dst[e]], 1.0f);
}

// thread per (node, quad): y[n, 4q..4q+3] = x[n, 4q..4q+3]/deg[n].
// q==0 thread also emits dinv[n] = rsqrt(deg[n]).
__global__ void k_selfloop(const float* __restrict__ state,
                           const float* __restrict__ edge_attr,
                           const float* __restrict__ deg,
                           float* __restrict__ dinv,
                           float* __restrict__ y,
                           int N, int Ns) {
  int tid = blockIdx.x * blockDim.x + threadIdx.x;
  if (tid >= N * 5) return;
  int n = tid / 5;
  int q = tid - n * 5;
  float d = deg[n];
  float inv = 1.0f / d;
  const float* xrow = (n < Ns) ? (state + (size_t)n * F)
                               : (edge_attr + (size_t)(n - Ns) * F);
  float4 v = *reinterpret_cast<const float4*>(xrow + q * 4);
  v.x *= inv; v.y *= inv; v.z *= inv; v.w *= inv;
  *reinterpret_cast<float4*>(y + (size_t)n * F + q * 4) = v;
  if (q == 0) dinv[n] = rsqrtf(d);
}

// thread per (edge, feature): y[dst,f] += dinv[src]*dinv[dst]*x[src,f].
// f-major lane mapping keeps each wave's atomic instruction within ~3 rows.
__global__ void k_edge_scatter(const int* __restrict__ src,
                               const int* __restrict__ dst,
                               const float* __restrict__ dinv,
                               const float* __restrict__ state,
                               const float* __restrict__ edge_attr,
                               float* __restrict__ y,
                               int E, int Ns) {
  int tid = blockIdx.x * blockDim.x + threadIdx.x;
  if (tid >= E * F) return;
  int e = tid / F;
  int f = tid - e * F;
  int s = src[e];
  int d = dst[e];
  float norm = dinv[s] * dinv[d];
  int xi = s * F + f;
  int sb = Ns * F;
  float x = (xi < sb) ? state[xi] : edge_attr[xi - sb];
  atomicAdd(&y[d * F + f], norm * x);
}

// Column sums + upper-tri second moments of y, LDS-staged.
// One 256-row chunk per block (814 blocks, ~12 waves/CU TLP); row loop
// unrolled x4 with independent accumulators; one atomicAdd per stat per block.
#define SROWS 256
__global__ __launch_bounds__(256) void k_stats(const float* __restrict__ y,
                                               float* __restrict__ stats, int N) {
  __shared__ float lds[SROWS * F];  // 20 KB
  int c = threadIdx.x;
  int ci = 0, cj = 0;
  if (c >= F && c < NSTAT) {
    int k = c - F;
    int i = 0;
    while (k >= F - i) { k -= F - i; i++; }
    ci = i; cj = i + k;
  }
  long e0 = (long)blockIdx.x * (SROWS * F);
  long totalElems = (long)N * F;
  for (int i4 = c; i4 < SROWS * F / 4; i4 += 256) {
    long gi = e0 + (long)i4 * 4;
    float4 v;
    if (gi + 3 < totalElems) {
      v = *reinterpret_cast<const float4*>(y + gi);
    } else {
      v.x = v.y = v.z = v.w = 0.f;
    }
    *reinterpret_cast<float4*>(lds + i4 * 4) = v;
  }
  __syncthreads();
  if (c < F) {
    float a0 = 0.f, a1 = 0.f, a2 = 0.f, a3 = 0.f;
    for (int r = 0; r < SROWS; r += 4) {
      a0 += lds[(r + 0) * F + c];
      a1 += lds[(r + 1) * F + c];
      a2 += lds[(r + 2) * F + c];
      a3 += lds[(r + 3) * F + c];
    }
    atomicAdd(&stats[c], (a0 + a1) + (a2 + a3));
  } else if (c < NSTAT) {
    float a0 = 0.f, a1 = 0.f, a2 = 0.f, a3 = 0.f;
    for (int r = 0; r < SROWS; r += 4) {
      a0 += lds[(r + 0) * F + ci] * lds[(r + 0) * F + cj];
      a1 += lds[(r + 1) * F + ci] * lds[(r + 1) * F + cj];
      a2 += lds[(r + 2) * F + ci] * lds[(r + 2) * F + cj];
      a3 += lds[(r + 3) * F + ci] * lds[(r + 3) * F + cj];
    }
    atomicAdd(&stats[c], (a0 + a1) + (a2 + a3));
  }
}

// Single block, 256 threads, launch_bounds(256,1): 4 waves -> up to 512
// VGPR/thread, so w[4][20] + m0[20] + m1[20] live in registers (rounds 2-3
// at 1024 threads were capped at 64 VGPR -> scratch spill).
__global__ __launch_bounds__(256, 1) void k_finalize(
    const float* __restrict__ stats,
    const float* __restrict__ W_gcn,
    const float* __restrict__ gamma,
    const float* __restrict__ beta,
    const float* __restrict__ W_lin,
    const float* __restrict__ b_lin,
    float* __restrict__ params,
    int N, int H) {
  __shared__ float Cu_s[210];
  __shared__ float ybar_s[F];
  __shared__ float part[4][44];
  int t = threadIdx.x;
  int lane = t & 63;
  int wv = t >> 6;
  float invN = 1.0f / (float)N;
  if (t < F) ybar_s[t] = stats[t] * invN;
  __syncthreads();
  if (t < 210) {
    int k = t;
    int i = 0;
    while (k >= F - i) { k -= F - i; i++; }
    int j = i + k;
    float cv = stats[F + t] * invN - ybar_s[i] * ybar_s[j];
    Cu_s[t] = (i == j) ? cv : 2.0f * cv;  // fold symmetry factor
  }
  __syncthreads();

  float m0[F], m1[F];
  #pragma unroll
  for (int f = 0; f < F; ++f) { m0[f] = 0.f; m1[f] = 0.f; }
  float d0 = 0.f, d1 = 0.f;

  for (int hb = 0; hb < H; hb += 4 * 256) {
    float w[4][F];
    float var[4];
    int hh[4];
    bool act[4];
    #pragma unroll
    for (int c = 0; c < 4; ++c) {
      int h = hb + c * 256 + t;
      act[c] = (h < H);
      hh[c] = act[c] ? h : 0;
      var[c] = 0.f;
      #pragma unroll
      for (int f = 0; f < F; ++f) {
        float x = W_gcn[f * H + hh[c]];  // coalesced over t
        w[c][f] = act[c] ? x : 0.f;
      }
    }
    int p = 0;
    #pragma unroll
    for (int i = 0; i < F; ++i) {
      #pragma unroll
      for (int j = i; j < F; ++j) {
        float cu = Cu_s[p];  // uniform broadcast, reused 4x
        ++p;
        #pragma unroll
        for (int c = 0; c < 4; ++c) var[c] += cu * (w[c][i] * w[c][j]);
      }
    }
    #pragma unroll
    for (int c = 0; c < 4; ++c) {
      float sg = act[c] ? (gamma[hh[c]] * rsqrtf(var[c] + 1e-5f)) : 0.f;
      float wl0 = W_lin[hh[c] * 2 + 0], wl1 = W_lin[hh[c] * 2 + 1];
      float s0 = sg * wl0, s1 = sg * wl1;
      #pragma unroll
      for (int f = 0; f < F; ++f) { m0[f] += w[c][f] * s0; m1[f] += w[c][f] * s1; }
      float bt = act[c] ? beta[hh[c]] : 0.f;
      d0 += bt * wl0;
      d1 += bt * wl1;
    }
  }

  // one butterfly reduce at the end
  #pragma unroll
  for (int f = 0; f < F; ++f) {
    float v0 = m0[f], v1 = m1[f];
    #pragma unroll
    for (int off = 32; off; off >>= 1) {
      v0 += __shfl_xor(v0, off);
      v1 += __shfl_xor(v1, off);
    }
    if (lane == 0) { part[wv][2 * f] = v0; part[wv][2 * f + 1] = v1; }
  }
  #pragma unroll
  for (int off = 32; off; off >>= 1) {
    d0 += __shfl_xor(d0, off);
    d1 += __shfl_xor(d1, off);
  }
  if (lane == 0) { part[wv][40] = d0; part[wv][41] = d1; }
  __syncthreads();

  if (t < 42) {
    float acc = 0.f;
    for (int w2 = 0; w2 < 4; ++w2) acc += part[w2][t];
    if (t >= 40) acc += b_lin[t - 40];
    params[t] = acc;
  } else if (t < 62) {
    params[t] = ybar_s[t - 42];
  }
}

// thread per node: logits = (y[n]-ybar) @ M + d; relu; 2-way softmax.
__global__ void k_out(const float* __restrict__ y,
                      const float* __restrict__ params,
                      float* __restrict__ out, int N) {
  __shared__ float P[64];
  if (threadIdx.x < 62) P[threadIdx.x] = params[threadIdx.x];
  __syncthreads();
  int n = blockIdx.x * blockDim.x + threadIdx.x;
  if (n >= N) return;
  const float4* yr4 = reinterpret_cast<const float4*>(y + (size_t)n * F);
  float v[F];
  #pragma unroll
  for (int k = 0; k < 5; ++k) {
    float4 q = yr4[k];
    v[4 * k + 0] = q.x; v[4 * k + 1] = q.y;
    v[4 * k + 2] = q.z; v[4 * k + 3] = q.w;
  }
  float l0 = P[40], l1 = P[41];
  #pragma unroll
  for (int f = 0; f < F; ++f) {
    float dv = v[f] - P[42 + f];
    l0 += dv * P[f * 2 + 0];
    l1 += dv * P[f * 2 + 1];
  }
  l0 = fmaxf(l0, 0.f);
  l1 = fmaxf(l1, 0.f);
  float m = fmaxf(l0, l1);
  float e0 = __expf(l0 - m), e1 = __expf(l1 - m);
  float inv = 1.0f / (e0 + e1);
  float2 o2; o2.x = e0 * inv; o2.y = e1 * inv;
  reinterpret_cast<float2*>(out)[n] = o2;
}

extern "C" void kernel_launch(void* const* d_in, const int* in_sizes, int n_in,
                              void* d_out, int out_size, void* d_ws, size_t ws_size,
                              hipStream_t stream) {
  const float* state     = (const float*)d_in[0];
  const float* edge_attr = (const float*)d_in[1];
  const int*   eidx      = (const int*)d_in[2];
  const float* W_gcn     = (const float*)d_in[3];
  // d_in[4] = b_gcn: cancels inside batchnorm, unused.
  const float* gamma     = (const float*)d_in[5];
  const float* beta      = (const float*)d_in[6];
  const float* W_lin     = (const float*)d_in[7];
  const float* b_lin     = (const float*)d_in[8];
  float* out = (float*)d_out;

  int Ns = in_sizes[0] / F;
  int E  = in_sizes[2] / 2;
  int N  = Ns + in_sizes[1] / F;
  int H  = in_sizes[4];

  const int* src = eidx;
  const int* dst = eidx + E;

  float* ws     = (float*)d_ws;
  float* deg    = ws;
  float* dinv   = ws + N;
  float* y      = ws + 2 * (size_t)N;
  float* stats  = y + (size_t)N * F;
  float* params = stats + 256;

  const int B = 256;
  k_deg_init<<<(N + B - 1) / B, B, 0, stream>>>(deg, stats, N);
  k_deg_acc<<<(E + B - 1) / B, B, 0, stream>>>(dst, deg, E);
  k_selfloop<<<(N * 5 + B - 1) / B, B, 0, stream>>>(state, edge_attr, deg, dinv, y, N, Ns);
  k_edge_scatter<<<(E * F + B - 1) / B, B, 0, stream>>>(src, dst, dinv, state, edge_attr, y, E, Ns);
  k_stats<<<(N + SROWS - 1) / SROWS, B, 0, stream>>>(y, stats, N);
  k_finalize<<<1, 256, 0, stream>>>(stats, W_gcn, gamma, beta, W_lin, b_lin, params, N, H);
  k_out<<<(N + B - 1) / B, B, 0, stream>>>(y, params, out, N);
}